// Round 1
// baseline (930.971 us; speedup 1.0000x reference)
//
#include <hip/hip_runtime.h>
#include <math.h>

#define IMG 384
#define ROWS 24
#define NIMG 128
#define LSEQ 128
#define CH 3

// total output image elements: 128*3*384*384 = 56,623,104
static constexpr unsigned int OUT_ELEMS = (unsigned int)NIMG * CH * IMG * IMG;
static constexpr unsigned int NV = OUT_ELEMS / 4;          // float4 groups = 14,155,776
static constexpr unsigned int BLOCK = 256;
static constexpr unsigned int GRID = NV / BLOCK;           // 55296 exactly

__device__ __forceinline__ float fast_tanh(float x) {
    // tanh(x) = sign(x) * (1 - 2/(e^{2|x|}+1)); overflow -> e=inf -> 1. Abs err ~1e-6.
    float ax = fabsf(x);
    float e  = __expf(2.0f * ax);
    float t  = 1.0f - 2.0f / (e + 1.0f);
    return copysignf(t, x);
}

__global__ __launch_bounds__(BLOCK) void reprog_main(
    const int*   __restrict__ sent,    // (128,128) token ids (int32)
    const float* __restrict__ table,   // (50257,768)
    float*       __restrict__ out,     // (128,3,384,384) flat
    double*      __restrict__ accum)   // sum of squares accumulator
{
    unsigned int idx = blockIdx.x * BLOCK + threadIdx.x;
    float lsum = 0.0f;

    if (idx < NV) {
        unsigned int q = idx * 4u;                 // global float index, < 2^26, fits u32
        unsigned int j  = q % IMG;                 // column (j%4 == 0 by construction)
        unsigned int t1 = q / IMG;
        unsigned int i  = t1 % IMG;                // row
        unsigned int t2 = t1 / IMG;
        unsigned int c  = t2 % CH;                 // channel
        unsigned int n  = t2 / CH;                 // image

        unsigned int r1 = i >> 4, r2 = j >> 4;
        unsigned int p  = r1 * ROWS + r2;          // patch index 0..575
        unsigned int l  = p < (LSEQ - 1) ? p : (LSEQ - 1);
        int tok = sent[n * LSEQ + l];

        unsigned int off = c * 256u + (i & 15u) * 16u + (j & 15u); // 0..767, %4==0
        const float4 v = *(const float4*)(table + (size_t)tok * 768u + off);

        float4 r;
        r.x = fast_tanh(v.x);
        r.y = fast_tanh(v.y);
        r.z = fast_tanh(v.z);
        r.w = fast_tanh(v.w);

        lsum = r.x * r.x + r.y * r.y + r.z * r.z + r.w * r.w;

        *(float4*)(out + q) = r;
    }

    // wave (64-lane) reduction
    #pragma unroll
    for (int o = 32; o > 0; o >>= 1)
        lsum += __shfl_down(lsum, o, 64);

    __shared__ float wsum[BLOCK / 64];
    unsigned int lane = threadIdx.x & 63u;
    unsigned int wave = threadIdx.x >> 6;
    if (lane == 0) wsum[wave] = lsum;
    __syncthreads();

    if (threadIdx.x == 0) {
        float s = wsum[0] + wsum[1] + wsum[2] + wsum[3];
        atomicAdd(accum, (double)s);
    }
}

__global__ void reprog_finalize(const double* __restrict__ accum,
                                float* __restrict__ out_scalar)
{
    if (threadIdx.x == 0 && blockIdx.x == 0)
        out_scalar[0] = (float)(sqrt(accum[0]) / (double)NIMG);
}

extern "C" void kernel_launch(void* const* d_in, const int* in_sizes, int n_in,
                              void* d_out, int out_size, void* d_ws, size_t ws_size,
                              hipStream_t stream) {
    const int*   sent  = (const int*)d_in[0];     // (128,128) int
    const float* table = (const float*)d_in[1];   // (50257,768) f32
    float*       out   = (float*)d_out;           // 56,623,104 + 1 floats
    double*      accum = (double*)d_ws;

    // ws is poisoned 0xAA before every timed call — zero the accumulator.
    hipMemsetAsync(d_ws, 0, sizeof(double), stream);

    reprog_main<<<GRID, BLOCK, 0, stream>>>(sent, table, out, accum);
    reprog_finalize<<<1, 64, 0, stream>>>(accum, out + OUT_ELEMS);
}

// Round 3
// 331.140 us; speedup vs baseline: 2.8114x; 2.8114x over previous
//
#include <hip/hip_runtime.h>
#include <math.h>

#define IMG 384
#define ROWS 24
#define NIMG 128
#define LSEQ 128
#define CH 3

// total output image elements: 128*3*384*384 = 56,623,104
static constexpr unsigned int OUT_ELEMS = (unsigned int)NIMG * CH * IMG * IMG;
static constexpr unsigned int NV = OUT_ELEMS / 4;   // float4 groups = 14,155,776
static constexpr unsigned int BLOCK = 256;
static constexpr unsigned int GRID = 6912;          // 6912*256*8 == NV exactly
static constexpr unsigned int PER_THREAD = 8;

// native clang vector type — required by __builtin_nontemporal_store
typedef float vfloat4 __attribute__((ext_vector_type(4)));

__device__ __forceinline__ float fast_tanh(float x) {
    // tanh(x) = sign(x) * (1 - 2/(e^{2|x|}+1)); overflow -> e=inf -> 1. Abs err ~1e-6.
    float ax = fabsf(x);
    float e  = __expf(2.0f * ax);
    float t  = 1.0f - 2.0f / (e + 1.0f);
    return copysignf(t, x);
}

__global__ __launch_bounds__(BLOCK) void reprog_main(
    const int*   __restrict__ sent,      // (128,128) token ids (int32)
    const float* __restrict__ table,     // (50257,768)
    float*       __restrict__ out,       // (128,3,384,384) flat
    float*       __restrict__ partials)  // (GRID) per-block sum of squares
{
    const unsigned int stride = GRID * BLOCK;
    unsigned int idx = blockIdx.x * BLOCK + threadIdx.x;
    float lsum = 0.0f;

    #pragma unroll
    for (unsigned int k = 0; k < PER_THREAD; ++k, idx += stride) {
        unsigned int q = idx * 4u;                 // global float index, < 2^26
        unsigned int j  = q % IMG;                 // column (j%4 == 0)
        unsigned int t1 = q / IMG;
        unsigned int i  = t1 % IMG;                // row
        unsigned int t2 = t1 / IMG;
        unsigned int c  = t2 % CH;                 // channel
        unsigned int n  = t2 / CH;                 // image

        unsigned int r1 = i >> 4, r2 = j >> 4;
        unsigned int p  = r1 * ROWS + r2;          // patch index 0..575
        unsigned int l  = p < (LSEQ - 1) ? p : (LSEQ - 1);
        int tok = sent[n * LSEQ + l];

        unsigned int off = c * 256u + (i & 15u) * 16u + (j & 15u); // 0..767, %4==0
        const vfloat4 v = *(const vfloat4*)(table + (size_t)tok * 768u + off);

        vfloat4 r;
        r.x = fast_tanh(v.x);
        r.y = fast_tanh(v.y);
        r.z = fast_tanh(v.z);
        r.w = fast_tanh(v.w);

        lsum += r.x * r.x + r.y * r.y + r.z * r.z + r.w * r.w;

        // stream the write — out is never re-read; keep table hot in L2/L3
        __builtin_nontemporal_store(r, (vfloat4*)(out + q));
    }

    // wave (64-lane) reduction
    #pragma unroll
    for (int o = 32; o > 0; o >>= 1)
        lsum += __shfl_down(lsum, o, 64);

    __shared__ float wsum[BLOCK / 64];
    unsigned int lane = threadIdx.x & 63u;
    unsigned int wave = threadIdx.x >> 6;
    if (lane == 0) wsum[wave] = lsum;
    __syncthreads();

    if (threadIdx.x == 0)
        partials[blockIdx.x] = wsum[0] + wsum[1] + wsum[2] + wsum[3];
}

__global__ __launch_bounds__(1024) void reprog_finalize(
    const float* __restrict__ partials,
    float*       __restrict__ out_scalar)
{
    double s = 0.0;
    for (unsigned int i = threadIdx.x; i < GRID; i += 1024)
        s += (double)partials[i];

    // wave reduction in double
    #pragma unroll
    for (int o = 32; o > 0; o >>= 1)
        s += __shfl_down(s, o, 64);

    __shared__ double wsum[16];
    unsigned int lane = threadIdx.x & 63u;
    unsigned int wave = threadIdx.x >> 6;
    if (lane == 0) wsum[wave] = s;
    __syncthreads();

    if (threadIdx.x == 0) {
        double t = 0.0;
        #pragma unroll
        for (int w = 0; w < 16; ++w) t += wsum[w];
        out_scalar[0] = (float)(sqrt(t) / (double)NIMG);
    }
}

extern "C" void kernel_launch(void* const* d_in, const int* in_sizes, int n_in,
                              void* d_out, int out_size, void* d_ws, size_t ws_size,
                              hipStream_t stream) {
    const int*   sent  = (const int*)d_in[0];     // (128,128) int
    const float* table = (const float*)d_in[1];   // (50257,768) f32
    float*       out   = (float*)d_out;           // 56,623,104 + 1 floats
    float*       partials = (float*)d_ws;         // GRID floats

    reprog_main<<<GRID, BLOCK, 0, stream>>>(sent, table, out, partials);
    reprog_finalize<<<1, 1024, 0, stream>>>(partials, out + OUT_ELEMS);
}

// Round 4
// 328.667 us; speedup vs baseline: 2.8326x; 1.0075x over previous
//
#include <hip/hip_runtime.h>
#include <math.h>

#define IMG 384
#define ROWS 24
#define NIMG 128
#define LSEQ 128
#define CH 3

// total output image elements: 128*3*384*384 = 56,623,104
static constexpr unsigned int OUT_ELEMS = (unsigned int)NIMG * CH * IMG * IMG;
static constexpr unsigned int NV = OUT_ELEMS / 4;   // float4 groups = 14,155,776
static constexpr unsigned int BLOCK = 256;
static constexpr unsigned int GRID = 6912;          // 6912*256*8 == NV exactly
static constexpr unsigned int PER_THREAD = 8;
// grid stride in floats = 6912*256*4 = 7,077,888 = exactly 48 planes (16 images x 3ch)
// => (i, j, c) are invariant across the 8 per-thread iterations; n += 16 each.
static constexpr unsigned int STRIDE_FLOATS = GRID * BLOCK * 4u;

// native clang vector type — required by __builtin_nontemporal_store
typedef float vfloat4 __attribute__((ext_vector_type(4)));

__device__ __forceinline__ float fast_tanh(float x) {
    // tanh(x) = sign(x) * (1 - 2/(e^{2|x|}+1)); overflow -> e=inf -> 1. Abs err ~1e-6.
    float ax = fabsf(x);
    float e  = __expf(2.0f * ax);
    float t  = 1.0f - 2.0f / (e + 1.0f);
    return copysignf(t, x);
}

__global__ __launch_bounds__(BLOCK) void reprog_main(
    const int*   __restrict__ sent,      // (128,128) token ids (int32)
    const float* __restrict__ table,     // (50257,768)
    float*       __restrict__ out,       // (128,3,384,384) flat
    float*       __restrict__ partials)  // (GRID) per-block sum of squares
{
    const unsigned int idx = blockIdx.x * BLOCK + threadIdx.x; // [0, 1769472)
    const unsigned int q0  = idx * 4u;          // initial float index, < 7,077,888

    // Invariant decomposition (t2 in [0,48), so c fixed, n0 in [0,16)):
    const unsigned int j  = q0 % IMG;
    const unsigned int t1 = q0 / IMG;
    const unsigned int i  = t1 % IMG;
    const unsigned int t2 = t1 / IMG;
    const unsigned int c  = t2 % CH;
    const unsigned int n0 = t2 / CH;

    const unsigned int p  = (i >> 4) * ROWS + (j >> 4);       // patch 0..575
    const unsigned int l  = p < (LSEQ - 1) ? p : (LSEQ - 1);
    const unsigned int off = c * 256u + (i & 15u) * 16u + (j & 15u); // 0..767, %4==0

    const int*   sent_base = sent + l + (size_t)n0 * LSEQ;    // advance by 16*128 per k
    const float* tab_base  = table + off;                     // + tok*768
    float*       out_base  = out + q0;                        // advance by STRIDE_FLOATS per k

    // 8 independent token loads (addresses known upfront), then 8 gathers.
    int tok[PER_THREAD];
    #pragma unroll
    for (unsigned int k = 0; k < PER_THREAD; ++k)
        tok[k] = sent_base[(size_t)k * 16u * LSEQ];

    float lsum = 0.0f;
    #pragma unroll
    for (unsigned int k = 0; k < PER_THREAD; ++k) {
        const vfloat4 v = *(const vfloat4*)(tab_base + (size_t)tok[k] * 768u);
        vfloat4 r;
        r.x = fast_tanh(v.x);
        r.y = fast_tanh(v.y);
        r.z = fast_tanh(v.z);
        r.w = fast_tanh(v.w);
        lsum += r.x * r.x + r.y * r.y + r.z * r.z + r.w * r.w;
        // stream the write — out is never re-read; keep table hot in L2/L3
        __builtin_nontemporal_store(r, (vfloat4*)(out_base + (size_t)k * STRIDE_FLOATS));
    }

    // wave (64-lane) reduction
    #pragma unroll
    for (int o = 32; o > 0; o >>= 1)
        lsum += __shfl_down(lsum, o, 64);

    __shared__ float wsum[BLOCK / 64];
    unsigned int lane = threadIdx.x & 63u;
    unsigned int wave = threadIdx.x >> 6;
    if (lane == 0) wsum[wave] = lsum;
    __syncthreads();

    if (threadIdx.x == 0)
        partials[blockIdx.x] = wsum[0] + wsum[1] + wsum[2] + wsum[3];
}

__global__ __launch_bounds__(1024) void reprog_finalize(
    const float* __restrict__ partials,
    float*       __restrict__ out_scalar)
{
    double s = 0.0;
    for (unsigned int i = threadIdx.x; i < GRID; i += 1024)
        s += (double)partials[i];

    // wave reduction in double
    #pragma unroll
    for (int o = 32; o > 0; o >>= 1)
        s += __shfl_down(s, o, 64);

    __shared__ double wsum[16];
    unsigned int lane = threadIdx.x & 63u;
    unsigned int wave = threadIdx.x >> 6;
    if (lane == 0) wsum[wave] = s;
    __syncthreads();

    if (threadIdx.x == 0) {
        double t = 0.0;
        #pragma unroll
        for (int w = 0; w < 16; ++w) t += wsum[w];
        out_scalar[0] = (float)(sqrt(t) / (double)NIMG);
    }
}

extern "C" void kernel_launch(void* const* d_in, const int* in_sizes, int n_in,
                              void* d_out, int out_size, void* d_ws, size_t ws_size,
                              hipStream_t stream) {
    const int*   sent  = (const int*)d_in[0];     // (128,128) int
    const float* table = (const float*)d_in[1];   // (50257,768) f32
    float*       out   = (float*)d_out;           // 56,623,104 + 1 floats
    float*       partials = (float*)d_ws;         // GRID floats

    reprog_main<<<GRID, BLOCK, 0, stream>>>(sent, table, out, partials);
    reprog_finalize<<<1, 1024, 0, stream>>>(partials, out + OUT_ELEMS);
}